// Round 2
// baseline (201.537 us; speedup 1.0000x reference)
//
#include <hip/hip_runtime.h>

#define SEQ 2048
#define HEADS 16
#define DEPTH 64
#define DIMS 1024

typedef __bf16 bf16x8 __attribute__((ext_vector_type(8)));
typedef float f32x4 __attribute__((ext_vector_type(4)));

__device__ __forceinline__ f32x4 mfma16(bf16x8 a, bf16x8 b, f32x4 c) {
  return __builtin_amdgcn_mfma_f32_16x16x32_bf16(a, b, c, 0, 0, 0);
}

// LDS row strides (bf16 elems), padded so fragment ds_read_b128 spreads
// uniformly across the 8 16B bank-groups:
//   K tiles [32][64] -> stride 72 (144B = 9 slots, gcd(9,8)=1)
//   V^T    [64][32] -> stride 40 ( 80B = 5 slots, gcd(5,8)=1)
#define KLD 72
#define VLD 40

__global__ __launch_bounds__(256) void attn_fwd(
    const float* __restrict__ q, const float* __restrict__ k,
    const float* __restrict__ v, float* __restrict__ out) {
  __shared__ __bf16 Khi[32 * KLD];
  __shared__ __bf16 Klo[32 * KLD];
  __shared__ __bf16 Vt[64 * VLD];
  __shared__ __bf16 Pl[4][16 * 32];

  const int tid = threadIdx.x;
  const int w = tid >> 6;        // wave 0..3
  const int l = tid & 63;        // lane
  const int lg = l >> 4;         // lane group 0..3
  const int lr = l & 15;         // lane row/col 0..15

  const int bid = blockIdx.x;
  const int qt = bid & 31;       // q-tile (64 rows each)
  const int bh = bid >> 5;
  const int h = bh & 15;
  const int b = bh >> 4;

  const int qbase = qt * 64 + w * 16;
  const int hoff = h * DEPTH;

  // ---- Q fragments hi/lo: A[m=lr][d = 32c + 8*lg + j], fp32 -> bf16 split --
  bf16x8 qhi[2], qlo[2];
  {
    const float* gq = q + (size_t)(b * SEQ + qbase + lr) * DIMS + hoff + 8 * lg;
    for (int c = 0; c < 2; ++c) {
      float4 a0 = *(const float4*)(gq + 32 * c);
      float4 a1 = *(const float4*)(gq + 32 * c + 4);
      float f[8] = {a0.x, a0.y, a0.z, a0.w, a1.x, a1.y, a1.z, a1.w};
      bf16x8 th, tl;
      #pragma unroll
      for (int j = 0; j < 8; ++j) {
        __bf16 hi = (__bf16)f[j];
        th[j] = hi;
        tl[j] = (__bf16)(f[j] - (float)hi);
      }
      qhi[c] = th;
      qlo[c] = tl;
    }
  }

  f32x4 acc[4] = {};                 // O accumulator: 4 d-tiles of 16
  float m[4], sden[4];
  for (int r = 0; r < 4; ++r) { m[r] = -1e30f; sden[r] = 0.f; }

  for (int kt = 0; kt < SEQ / 32; ++kt) {
    const int kb = kt * 32;
    __syncthreads();  // protect LDS WAR vs previous iteration's reads

    // ---- stage K tile [32 x 64] row-major bf16, hi + lo ----
    {
      const int r = tid >> 3;            // 0..31
      const int c0 = (tid & 7) * 8;      // 0,8,..,56
      const float* gk = k + (size_t)(b * SEQ + kb + r) * DIMS + hoff + c0;
      float4 a0 = *(const float4*)gk;
      float4 a1 = *(const float4*)(gk + 4);
      float f[8] = {a0.x, a0.y, a0.z, a0.w, a1.x, a1.y, a1.z, a1.w};
      bf16x8 th, tl;
      #pragma unroll
      for (int j = 0; j < 8; ++j) {
        __bf16 hi = (__bf16)f[j];
        th[j] = hi;
        tl[j] = (__bf16)(f[j] - (float)hi);
      }
      *(bf16x8*)&Khi[r * KLD + c0] = th;
      *(bf16x8*)&Klo[r * KLD + c0] = tl;
    }
    // ---- stage V^T [64 d][32 k]: wave w takes k-rows 8w..8w+7, lane = d col
    {
      const float* gv = v + (size_t)(b * SEQ + kb + 8 * w) * DIMS + hoff + l;
      bf16x8 t;
      #pragma unroll
      for (int i = 0; i < 8; ++i) t[i] = (__bf16)gv[(size_t)i * DIMS];
      *(bf16x8*)&Vt[l * VLD + 8 * w] = t;
    }
    __syncthreads();

    // ---- QK^T (split precision): S = Qhi*Khi + Qhi*Klo + Qlo*Khi ----
    f32x4 s0 = {}, s1 = {};
    #pragma unroll
    for (int c = 0; c < 2; ++c) {
      bf16x8 kh0 = *(const bf16x8*)&Khi[lr * KLD + 32 * c + 8 * lg];
      bf16x8 kl0 = *(const bf16x8*)&Klo[lr * KLD + 32 * c + 8 * lg];
      s0 = mfma16(qhi[c], kh0, s0);
      s0 = mfma16(qhi[c], kl0, s0);
      s0 = mfma16(qlo[c], kh0, s0);
      bf16x8 kh1 = *(const bf16x8*)&Khi[(16 + lr) * KLD + 32 * c + 8 * lg];
      bf16x8 kl1 = *(const bf16x8*)&Klo[(16 + lr) * KLD + 32 * c + 8 * lg];
      s1 = mfma16(qhi[c], kh1, s1);
      s1 = mfma16(qhi[c], kl1, s1);
      s1 = mfma16(qlo[c], kh1, s1);
    }

    // ---- online softmax (rows live across 16-lane groups) ----
    #pragma unroll
    for (int r = 0; r < 4; ++r) {
      float v0 = s0[r], v1 = s1[r];
      float mx = fmaxf(v0, v1);
      mx = fmaxf(mx, __shfl_xor(mx, 1));
      mx = fmaxf(mx, __shfl_xor(mx, 2));
      mx = fmaxf(mx, __shfl_xor(mx, 4));
      mx = fmaxf(mx, __shfl_xor(mx, 8));
      float mnew = fmaxf(m[r], mx);
      float sc = __expf(m[r] - mnew);
      m[r] = mnew;
      float e0 = __expf(v0 - mnew);
      float e1 = __expf(v1 - mnew);
      __bf16 b0 = (__bf16)e0, b1 = (__bf16)e1;   // round P to bf16 NOW
      float rs = (float)b0 + (float)b1;           // so denom matches PV exactly
      rs += __shfl_xor(rs, 1);
      rs += __shfl_xor(rs, 2);
      rs += __shfl_xor(rs, 4);
      rs += __shfl_xor(rs, 8);
      sden[r] = sden[r] * sc + rs;
      acc[0][r] *= sc; acc[1][r] *= sc; acc[2][r] *= sc; acc[3][r] *= sc;
      const int prow = 4 * lg + r;
      Pl[w][prow * 32 + lr] = b0;
      Pl[w][prow * 32 + 16 + lr] = b1;
    }

    // ---- PV: A = P[16q x 32k] (wave-local LDS round-trip), B = V^T reads ----
    {
      bf16x8 pa = *(const bf16x8*)&Pl[w][lr * 32 + 8 * lg];
      #pragma unroll
      for (int dt = 0; dt < 4; ++dt) {
        bf16x8 vb = *(const bf16x8*)&Vt[(dt * 16 + lr) * VLD + 8 * lg];
        acc[dt] = mfma16(pa, vb, acc[dt]);
      }
    }
  }

  // ---- epilogue: normalize and store fp32 ----
  #pragma unroll
  for (int dt = 0; dt < 4; ++dt) {
    #pragma unroll
    for (int r = 0; r < 4; ++r) {
      const int row = qbase + 4 * lg + r;
      out[(size_t)(b * SEQ + row) * DIMS + hoff + dt * 16 + lr] =
          acc[dt][r] / sden[r];
    }
  }
}

extern "C" void kernel_launch(void* const* d_in, const int* in_sizes, int n_in,
                              void* d_out, int out_size, void* d_ws, size_t ws_size,
                              hipStream_t stream) {
  const float* q = (const float*)d_in[0];
  const float* k = (const float*)d_in[1];
  const float* v = (const float*)d_in[2];
  float* out = (float*)d_out;
  const int B = in_sizes[0] / (SEQ * DIMS);   // = 2
  dim3 grid(B * HEADS * (SEQ / 64));          // 1024 blocks
  attn_fwd<<<grid, 256, 0, stream>>>(q, k, v, out);
}

// Round 3
// 114.600 us; speedup vs baseline: 1.7586x; 1.7586x over previous
//
#include <hip/hip_runtime.h>

#define SEQ 2048
#define HEADS 16
#define DEPTH 64
#define DIMS 1024

typedef __bf16 bf16x8 __attribute__((ext_vector_type(8)));
typedef __bf16 bf16x4 __attribute__((ext_vector_type(4)));
typedef float f32x4 __attribute__((ext_vector_type(4)));

__device__ __forceinline__ f32x4 mfma16(bf16x8 a, bf16x8 b, f32x4 c) {
  return __builtin_amdgcn_mfma_f32_16x16x32_bf16(a, b, c, 0, 0, 0);
}

// ---------- prepass 1: K fp32 [B,S,DIMS] -> Khi/Klo bf16 [bh][S][D] ----------
__global__ __launch_bounds__(256) void prep_k(const float* __restrict__ k,
                                              __bf16* __restrict__ khi,
                                              __bf16* __restrict__ klo) {
  int t = blockIdx.x * 256 + threadIdx.x;       // one thread per 8 elems
  size_t flat = (size_t)t * 8;
  int b = (int)(flat >> 21);                    // S*DIMS = 2^21
  int rem = (int)(flat & ((1u << 21) - 1));
  int s = rem >> 10;
  int c = rem & 1023;
  int h = c >> 6;
  int d = c & 63;
  float4 a0 = *(const float4*)(k + flat);
  float4 a1 = *(const float4*)(k + flat + 4);
  float f[8] = {a0.x, a0.y, a0.z, a0.w, a1.x, a1.y, a1.z, a1.w};
  bf16x8 th, tl;
  #pragma unroll
  for (int j = 0; j < 8; ++j) {
    __bf16 hi = (__bf16)f[j];
    th[j] = hi;
    tl[j] = (__bf16)(f[j] - (float)hi);
  }
  size_t o = ((size_t)(b * HEADS + h) * SEQ + s) * DEPTH + d;
  *(bf16x8*)(khi + o) = th;
  *(bf16x8*)(klo + o) = tl;
}

// ---------- prepass 2: V fp32 [B,S,DIMS] -> Vt bf16 [bh][D][S] ----------
__global__ __launch_bounds__(256) void prep_v(const float* __restrict__ v,
                                              __bf16* __restrict__ vt) {
  int t = blockIdx.x * 256 + threadIdx.x;
  int d = t & 63;                // lanes cover d contiguously -> coalesced reads
  int sg = (t >> 6) & 255;
  int bh = t >> 14;
  int b = bh >> 4, h = bh & 15;
  int s0 = sg * 8;
  const float* src = v + ((size_t)(b * SEQ + s0)) * DIMS + h * DEPTH + d;
  __bf16* dst = vt + ((size_t)bh * DEPTH + d) * SEQ + s0;
  #pragma unroll
  for (int i = 0; i < 8; ++i) dst[i] = (__bf16)src[(size_t)i * DIMS];
}

// ---------- main: flash attention, KV tile 64, 32 q-rows/wave ----------
// LDS row stride 72 bf16 (144B): bank-quad = 4*((row+lg)%8) -> balanced b128.
#define LD 72

__global__ __launch_bounds__(256) void attn_fwd(
    const float* __restrict__ q, const __bf16* __restrict__ khi,
    const __bf16* __restrict__ klo, const __bf16* __restrict__ vt,
    float* __restrict__ out) {
  __shared__ __bf16 Khi[64 * LD];
  __shared__ __bf16 Klo[64 * LD];
  __shared__ __bf16 Vt[64 * LD];
  __shared__ __bf16 Pl[4][32 * LD];

  const int tid = threadIdx.x;
  const int w = tid >> 6;
  const int l = tid & 63;
  const int lg = l >> 4;
  const int lr = l & 15;

  // XCD-chunked bijective swizzle: 512 blocks, 8 XCDs, 64 per XCD.
  const int bid = blockIdx.x;
  const int wg = (bid & 7) * 64 + (bid >> 3);
  const int qt = wg & 15;        // q-tile of 128 rows
  const int bh = wg >> 4;        // 0..31
  const int b = bh >> 4;
  const int h = bh & 15;

  const int qb = qt * 128 + w * 32;      // wave's first q row
  const int hoff = h * DEPTH;
  const size_t kvoff = (size_t)bh * SEQ * DEPTH;

  // ---- Q fragments (B-layout: lane holds q-row = lr), fp32 -> hi/lo split --
  bf16x8 qhi[2][2], qlo[2][2];           // [mt][c]
  #pragma unroll
  for (int mt = 0; mt < 2; ++mt) {
    const float* gq =
        q + (size_t)(b * SEQ + qb + mt * 16 + lr) * DIMS + hoff + 8 * lg;
    #pragma unroll
    for (int c = 0; c < 2; ++c) {
      float4 a0 = *(const float4*)(gq + 32 * c);
      float4 a1 = *(const float4*)(gq + 32 * c + 4);
      float f[8] = {a0.x, a0.y, a0.z, a0.w, a1.x, a1.y, a1.z, a1.w};
      bf16x8 th, tl;
      #pragma unroll
      for (int j = 0; j < 8; ++j) {
        __bf16 hi = (__bf16)f[j];
        th[j] = hi;
        tl[j] = (__bf16)(f[j] - (float)hi);
      }
      qhi[mt][c] = th;
      qlo[mt][c] = tl;
    }
  }

  f32x4 acc[2][4] = {};                  // [mt][dt], C: q=mt*16+4lg+r, d=dt*16+lr
  float m[2] = {-1e30f, -1e30f};         // per-lane stats for q-row = lr
  float den[2] = {0.f, 0.f};

  for (int kt = 0; kt < SEQ / 64; ++kt) {
    const int kb = kt * 64;
    __syncthreads();                     // WAR: previous iter's reads done

    // ---- stage Khi/Klo [64][64] and Vt [64][64] (pure bf16 b128 copies) ----
    #pragma unroll
    for (int i = 0; i < 2; ++i) {
      const int c = tid + i * 256;
      const int r = c >> 3, ch = c & 7;
      *(bf16x8*)&Khi[r * LD + ch * 8] =
          *(const bf16x8*)(khi + kvoff + (size_t)(kb + r) * DEPTH + ch * 8);
      *(bf16x8*)&Klo[r * LD + ch * 8] =
          *(const bf16x8*)(klo + kvoff + (size_t)(kb + r) * DEPTH + ch * 8);
      *(bf16x8*)&Vt[r * LD + ch * 8] =
          *(const bf16x8*)(vt + kvoff + (size_t)r * SEQ + kb + ch * 8);
    }
    __syncthreads();

    // ---- QK^T swapped: S^T[key][q]; lane holds q=lr, keys nt*16+4lg+r ----
    f32x4 st[4][2] = {};                 // [nt][mt]
    #pragma unroll
    for (int nt = 0; nt < 4; ++nt) {
      #pragma unroll
      for (int c = 0; c < 2; ++c) {
        bf16x8 kh = *(const bf16x8*)&Khi[(nt * 16 + lr) * LD + c * 32 + 8 * lg];
        bf16x8 kl = *(const bf16x8*)&Klo[(nt * 16 + lr) * LD + c * 32 + 8 * lg];
        #pragma unroll
        for (int mt = 0; mt < 2; ++mt) {
          st[nt][mt] = mfma16(kh, qhi[mt][c], st[nt][mt]);
          st[nt][mt] = mfma16(kl, qhi[mt][c], st[nt][mt]);
          st[nt][mt] = mfma16(kh, qlo[mt][c], st[nt][mt]);
        }
      }
    }

    // ---- online softmax: row q=lr fully lane-local (16 vals) + 2 shfls ----
    #pragma unroll
    for (int mt = 0; mt < 2; ++mt) {
      float mx = st[0][mt][0];
      #pragma unroll
      for (int nt = 0; nt < 4; ++nt)
        #pragma unroll
        for (int r = 0; r < 4; ++r) mx = fmaxf(mx, st[nt][mt][r]);
      mx = fmaxf(mx, __shfl_xor(mx, 16));
      mx = fmaxf(mx, __shfl_xor(mx, 32));
      float mnew = fmaxf(m[mt], mx);
      float sc = __expf(m[mt] - mnew);
      m[mt] = mnew;
      float p[4][4];
      float rs = 0.f;
      #pragma unroll
      for (int nt = 0; nt < 4; ++nt)
        #pragma unroll
        for (int r = 0; r < 4; ++r) {
          p[nt][r] = __expf(st[nt][mt][r] - mnew);
          rs += p[nt][r];
        }
      rs += __shfl_xor(rs, 16);
      rs += __shfl_xor(rs, 32);
      den[mt] = den[mt] * sc + rs;
      // broadcast sc to the acc layout rows (q = 4lg+r lives at lane lr=4lg+r)
      #pragma unroll
      for (int r = 0; r < 4; ++r) {
        float scb = __shfl(sc, (l & 48) | (4 * lg + r));
        #pragma unroll
        for (int dt = 0; dt < 4; ++dt) acc[mt][dt][r] *= scb;
      }
      // pack P row into LDS: row q = mt*16+lr, cols nt*16+4lg..+3 (b64 writes)
      #pragma unroll
      for (int nt = 0; nt < 4; ++nt) {
        bf16x4 pw = {(__bf16)p[nt][0], (__bf16)p[nt][1],
                     (__bf16)p[nt][2], (__bf16)p[nt][3]};
        *(bf16x4*)&Pl[w][(mt * 16 + lr) * LD + nt * 16 + 4 * lg] = pw;
      }
    }

    // ---- PV (normal orientation): A=P (lane-local rows), B=V^T ----
    #pragma unroll
    for (int ks = 0; ks < 2; ++ks) {
      bf16x8 pf0 = *(const bf16x8*)&Pl[w][(0 * 16 + lr) * LD + ks * 32 + 8 * lg];
      bf16x8 pf1 = *(const bf16x8*)&Pl[w][(1 * 16 + lr) * LD + ks * 32 + 8 * lg];
      #pragma unroll
      for (int dt = 0; dt < 4; ++dt) {
        bf16x8 vf = *(const bf16x8*)&Vt[(dt * 16 + lr) * LD + ks * 32 + 8 * lg];
        acc[0][dt] = mfma16(pf0, vf, acc[0][dt]);
        acc[1][dt] = mfma16(pf1, vf, acc[1][dt]);
      }
    }
  }

  // ---- epilogue: broadcast denominators, normalize, coalesced f32 stores ----
  #pragma unroll
  for (int mt = 0; mt < 2; ++mt) {
    float rden[4];
    #pragma unroll
    for (int r = 0; r < 4; ++r) {
      float dn = __shfl(den[mt], (l & 48) | (4 * lg + r));
      rden[r] = 1.0f / dn;
    }
    #pragma unroll
    for (int dt = 0; dt < 4; ++dt)
      #pragma unroll
      for (int r = 0; r < 4; ++r) {
        const int row = qb + mt * 16 + 4 * lg + r;
        out[(size_t)(b * SEQ + row) * DIMS + hoff + dt * 16 + lr] =
            acc[mt][dt][r] * rden[r];
      }
  }
}

extern "C" void kernel_launch(void* const* d_in, const int* in_sizes, int n_in,
                              void* d_out, int out_size, void* d_ws, size_t ws_size,
                              hipStream_t stream) {
  const float* q = (const float*)d_in[0];
  const float* k = (const float*)d_in[1];
  const float* v = (const float*)d_in[2];
  float* out = (float*)d_out;

  // workspace layout: Khi | Klo | Vt, each 2*16*2048*64 bf16 = 8 MiB
  const size_t tsz = (size_t)2 * HEADS * SEQ * DEPTH;  // elements
  __bf16* khi = (__bf16*)d_ws;
  __bf16* klo = khi + tsz;
  __bf16* vtp = klo + tsz;

  prep_k<<<2048, 256, 0, stream>>>(k, khi, klo);
  prep_v<<<2048, 256, 0, stream>>>(v, vtp);
  attn_fwd<<<512, 256, 0, stream>>>(q, khi, klo, vtp, out);
}

// Round 4
// 104.042 us; speedup vs baseline: 1.9371x; 1.1015x over previous
//
#include <hip/hip_runtime.h>

#define SEQ 2048
#define HEADS 16
#define DEPTH 64
#define DIMS 1024
#define LOG2E 1.44269504088896340736f

typedef __bf16 bf16x8 __attribute__((ext_vector_type(8)));
typedef __bf16 bf16x4 __attribute__((ext_vector_type(4)));
typedef float f32x4 __attribute__((ext_vector_type(4)));

__device__ __forceinline__ f32x4 mfma16(bf16x8 a, bf16x8 b, f32x4 c) {
  return __builtin_amdgcn_mfma_f32_16x16x32_bf16(a, b, c, 0, 0, 0);
}

#if __has_builtin(__builtin_amdgcn_exp2f)
#define EXP2(x) __builtin_amdgcn_exp2f(x)
#else
#define EXP2(x) exp2f(x)
#endif

// direct global->LDS DMA, 16B per lane; LDS dest = wave-uniform base + lane*16
#define GLOAD_LDS(g, l)                                                        \
  __builtin_amdgcn_global_load_lds(                                            \
      (const __attribute__((address_space(1))) unsigned int*)(g),              \
      (__attribute__((address_space(3))) unsigned int*)(l), 16, 0, 0)

// ---------- prepass 1: K fp32 [B,S,DIMS] -> Khi/Klo bf16 [bh][S][D] ----------
__global__ __launch_bounds__(256) void prep_k(const float* __restrict__ k,
                                              __bf16* __restrict__ khi,
                                              __bf16* __restrict__ klo) {
  int t = blockIdx.x * 256 + threadIdx.x;       // one thread per 8 elems
  size_t flat = (size_t)t * 8;
  int b = (int)(flat >> 21);                    // S*DIMS = 2^21
  int rem = (int)(flat & ((1u << 21) - 1));
  int s = rem >> 10;
  int c = rem & 1023;
  int h = c >> 6;
  int d = c & 63;
  float4 a0 = *(const float4*)(k + flat);
  float4 a1 = *(const float4*)(k + flat + 4);
  float f[8] = {a0.x, a0.y, a0.z, a0.w, a1.x, a1.y, a1.z, a1.w};
  bf16x8 th, tl;
  #pragma unroll
  for (int j = 0; j < 8; ++j) {
    __bf16 hi = (__bf16)f[j];
    th[j] = hi;
    tl[j] = (__bf16)(f[j] - (float)hi);
  }
  size_t o = ((size_t)(b * HEADS + h) * SEQ + s) * DEPTH + d;
  *(bf16x8*)(khi + o) = th;
  *(bf16x8*)(klo + o) = tl;
}

// ---------- prepass 2: V fp32 [B,S,DIMS] -> Vt bf16 [bh][D][S] ----------
__global__ __launch_bounds__(256) void prep_v(const float* __restrict__ v,
                                              __bf16* __restrict__ vt) {
  int t = blockIdx.x * 256 + threadIdx.x;
  int d = t & 63;                // lanes cover d contiguously -> coalesced reads
  int sg = (t >> 6) & 255;
  int bh = t >> 14;
  int b = bh >> 4, h = bh & 15;
  int s0 = sg * 8;
  const float* src = v + ((size_t)(b * SEQ + s0)) * DIMS + h * DEPTH + d;
  __bf16* dst = vt + ((size_t)bh * DEPTH + d) * SEQ + s0;
  bf16x8 tv;
  #pragma unroll
  for (int i = 0; i < 8; ++i) tv[i] = (__bf16)src[(size_t)i * DIMS];
  *(bf16x8*)dst = tv;            // 16B contiguous store
}

// ---------- main: flash attention, KV tile 64, 16 q-rows/wave ----------
// LDS tiles are linear [64][64] bf16 (128B rows). 16B chunks XOR-swizzled:
// data chunk c of row r lives at LDS chunk c^(r&7)  (source pre-swizzled for
// the global_load_lds-staged K/V; P is swizzled on both lane write and read).
__global__ __launch_bounds__(256, 4) void attn_fwd(
    const float* __restrict__ q, const __bf16* __restrict__ khi,
    const __bf16* __restrict__ klo, const __bf16* __restrict__ vt,
    float* __restrict__ out) {
  __shared__ __bf16 Khi[64 * 64];
  __shared__ __bf16 Klo[64 * 64];
  __shared__ __bf16 Vt[64 * 64];
  __shared__ __bf16 Pl[4][16 * 64];

  const int tid = threadIdx.x;
  const int w = tid >> 6;
  const int l = tid & 63;
  const int lg = l >> 4;
  const int lr = l & 15;

  // XCD-chunked bijective swizzle: 1024 blocks = 8 XCDs x 128; consecutive
  // wgs on one XCD share (b,h) -> its K/V panel stays in that XCD's L2.
  const int bid = blockIdx.x;
  const int wg = (bid & 7) * 128 + (bid >> 3);
  const int qt = wg & 31;        // q-tile of 64 rows
  const int bh = wg >> 5;        // 0..31
  const int b = bh >> 4;
  const int h = bh & 15;

  const int qb = qt * 64 + w * 16;       // wave's first q row
  const int hoff = h * DEPTH;
  const size_t kvoff = (size_t)bh * SEQ * DEPTH;

  // ---- Q fragments (B-layout: lane holds q-row = lr), scaled by log2e,
  //      fp32 -> bf16 hi/lo split ----
  bf16x8 qhi[2], qlo[2];
  {
    const float* gq = q + (size_t)(b * SEQ + qb + lr) * DIMS + hoff + 8 * lg;
    #pragma unroll
    for (int c = 0; c < 2; ++c) {
      float4 a0 = *(const float4*)(gq + 32 * c);
      float4 a1 = *(const float4*)(gq + 32 * c + 4);
      float f[8] = {a0.x, a0.y, a0.z, a0.w, a1.x, a1.y, a1.z, a1.w};
      bf16x8 th, tl;
      #pragma unroll
      for (int j = 0; j < 8; ++j) {
        float s = f[j] * LOG2E;
        __bf16 hi = (__bf16)s;
        th[j] = hi;
        tl[j] = (__bf16)(s - (float)hi);
      }
      qhi[c] = th;
      qlo[c] = tl;
    }
  }

  // ---- per-lane staging source pointers (source column pre-swizzled) ----
  const int srow = l >> 3;                       // row-in-8 handled by this lane
  const int scol = ((l & 7) ^ srow) * 8;         // inverse-swizzled column
  const __bf16* gkh = khi + kvoff + (size_t)(8 * w + srow) * DEPTH + scol;
  const __bf16* gkl = klo + kvoff + (size_t)(8 * w + srow) * DEPTH + scol;
  const __bf16* gv  = vt  + kvoff + (size_t)(8 * w + srow) * SEQ + scol;
  __bf16* lKh0 = &Khi[(8 * w) * 64];
  __bf16* lKh1 = &Khi[(32 + 8 * w) * 64];
  __bf16* lKl0 = &Klo[(8 * w) * 64];
  __bf16* lKl1 = &Klo[(32 + 8 * w) * 64];
  __bf16* lVt0 = &Vt[(8 * w) * 64];
  __bf16* lVt1 = &Vt[(32 + 8 * w) * 64];
  __bf16* Pw = &Pl[w][0];

  f32x4 acc[4] = {};            // C: q = 4*lg+r, d = dt*16+lr
  float mrow = -3e38f;          // log2-domain running max for q-row = lr
  float den = 0.f;

  // loop-invariant swizzled chunk offsets (elements)
  const int x7 = lr & 7;
  int kch[2], vch[2];
  #pragma unroll
  for (int c = 0; c < 2; ++c) kch[c] = ((4 * c + lg) ^ x7) * 8;
  vch[0] = kch[0]; vch[1] = kch[1];

  for (int kt = 0; kt < SEQ / 64; ++kt) {
    __syncthreads();            // all waves done reading previous tile
    GLOAD_LDS(gkh, lKh0);
    GLOAD_LDS(gkh + 32 * DEPTH, lKh1);
    GLOAD_LDS(gkl, lKl0);
    GLOAD_LDS(gkl + 32 * DEPTH, lKl1);
    GLOAD_LDS(gv, lVt0);
    GLOAD_LDS(gv + (size_t)32 * SEQ, lVt1);
    gkh += 64 * DEPTH;
    gkl += 64 * DEPTH;
    gv += 64;
    __syncthreads();            // drains vmcnt -> staged tile visible

    // ---- QK^T swapped: C[key][q]; lane holds q=lr, keys nt*16+4lg+r ----
    f32x4 st[4] = {};
    __builtin_amdgcn_s_setprio(1);
    #pragma unroll
    for (int nt = 0; nt < 4; ++nt) {
      #pragma unroll
      for (int c = 0; c < 2; ++c) {
        bf16x8 kh = *(const bf16x8*)&Khi[(nt * 16 + lr) * 64 + kch[c]];
        bf16x8 kl = *(const bf16x8*)&Klo[(nt * 16 + lr) * 64 + kch[c]];
        st[nt] = mfma16(kh, qhi[c], st[nt]);
        st[nt] = mfma16(kl, qhi[c], st[nt]);
        st[nt] = mfma16(kh, qlo[c], st[nt]);
      }
    }
    __builtin_amdgcn_s_setprio(0);

    // ---- online softmax in log2 domain, defer-max (THR=8) ----
    float pmax = st[0][0];
    #pragma unroll
    for (int nt = 0; nt < 4; ++nt)
      #pragma unroll
      for (int r = 0; r < 4; ++r) pmax = fmaxf(pmax, st[nt][r]);
    pmax = fmaxf(pmax, __shfl_xor(pmax, 16));
    pmax = fmaxf(pmax, __shfl_xor(pmax, 32));
    if (!__all(pmax - mrow <= 8.0f)) {
      float mnew = fmaxf(mrow, pmax);
      float sc = EXP2(mrow - mnew);
      mrow = mnew;
      den *= sc;
      #pragma unroll
      for (int r = 0; r < 4; ++r) {
        float scb = __shfl(sc, (l & 48) | (4 * lg + r));
        #pragma unroll
        for (int dt = 0; dt < 4; ++dt) acc[dt][r] *= scb;
      }
    }
    float p[4][4];
    float rs = 0.f;
    #pragma unroll
    for (int nt = 0; nt < 4; ++nt)
      #pragma unroll
      for (int r = 0; r < 4; ++r) {
        p[nt][r] = EXP2(st[nt][r] - mrow);
        rs += p[nt][r];
      }
    rs += __shfl_xor(rs, 16);
    rs += __shfl_xor(rs, 32);
    den += rs;

    // ---- pack P into LDS (swizzled, b64 writes): row q=lr, keys nt*16+4lg ----
    #pragma unroll
    for (int nt = 0; nt < 4; ++nt) {
      bf16x4 pw = {(__bf16)p[nt][0], (__bf16)p[nt][1],
                   (__bf16)p[nt][2], (__bf16)p[nt][3]};
      const int chunk = (2 * nt + (lg >> 1)) ^ x7;
      *(bf16x4*)&Pw[lr * 64 + chunk * 8 + (lg & 1) * 4] = pw;
    }

    // ---- PV: A = P (lane-local q rows), B = V^T; C: q=4lg+r, d=dt*16+lr ----
    __builtin_amdgcn_s_setprio(1);
    #pragma unroll
    for (int ks = 0; ks < 2; ++ks) {
      bf16x8 pf = *(const bf16x8*)&Pw[lr * 64 + vch[ks]];
      #pragma unroll
      for (int dt = 0; dt < 4; ++dt) {
        bf16x8 vf = *(const bf16x8*)&Vt[(dt * 16 + lr) * 64 + vch[ks]];
        acc[dt] = mfma16(pf, vf, acc[dt]);
      }
    }
    __builtin_amdgcn_s_setprio(0);
  }

  // ---- epilogue: broadcast denominators, normalize, coalesced f32 stores ----
  float rden[4];
  #pragma unroll
  for (int r = 0; r < 4; ++r)
    rden[r] = 1.0f / __shfl(den, (l & 48) | (4 * lg + r));
  #pragma unroll
  for (int dt = 0; dt < 4; ++dt)
    #pragma unroll
    for (int r = 0; r < 4; ++r) {
      const int row = qb + 4 * lg + r;
      out[(size_t)(b * SEQ + row) * DIMS + hoff + dt * 16 + lr] =
          acc[dt][r] * rden[r];
    }
}

extern "C" void kernel_launch(void* const* d_in, const int* in_sizes, int n_in,
                              void* d_out, int out_size, void* d_ws, size_t ws_size,
                              hipStream_t stream) {
  const float* q = (const float*)d_in[0];
  const float* k = (const float*)d_in[1];
  const float* v = (const float*)d_in[2];
  float* out = (float*)d_out;

  // workspace layout: Khi | Klo | Vt, each 2*16*2048*64 bf16 = 8 MiB
  const size_t tsz = (size_t)2 * HEADS * SEQ * DEPTH;  // elements
  __bf16* khi = (__bf16*)d_ws;
  __bf16* klo = khi + tsz;
  __bf16* vtp = klo + tsz;

  prep_k<<<2048, 256, 0, stream>>>(k, khi, klo);
  prep_v<<<2048, 256, 0, stream>>>(v, vtp);
  attn_fwd<<<1024, 256, 0, stream>>>(q, khi, klo, vtp, out);
}

// Round 6
// 77.732 us; speedup vs baseline: 2.5927x; 1.3385x over previous
//
#include <hip/hip_runtime.h>

#define SEQ 2048
#define HEADS 16
#define DEPTH 64
#define DIMS 1024
#define LOG2E 1.44269504088896340736f

typedef _Float16 f16x8 __attribute__((ext_vector_type(8)));
typedef _Float16 f16x4 __attribute__((ext_vector_type(4)));
typedef __fp16 fp16v2 __attribute__((ext_vector_type(2)));
typedef float f32x4 __attribute__((ext_vector_type(4)));

__device__ __forceinline__ f32x4 mfma16(f16x8 a, f16x8 b, f32x4 c) {
  return __builtin_amdgcn_mfma_f32_16x16x32_f16(a, b, c, 0, 0, 0);
}

#if __has_builtin(__builtin_amdgcn_exp2f)
#define EXP2(x) __builtin_amdgcn_exp2f(x)
#else
#define EXP2(x) exp2f(x)
#endif

// direct global->LDS DMA, 16B/lane; LDS dest = wave-uniform base + lane*16
#define GLOAD_LDS(g, l)                                                        \
  __builtin_amdgcn_global_load_lds(                                            \
      (const __attribute__((address_space(1))) unsigned int*)(g),              \
      (__attribute__((address_space(3))) unsigned int*)(l), 16, 0, 0)

// ---------- prepass 1: K fp32 [B,S,DIMS] -> fp16 [bh][S][D] ----------
__global__ __launch_bounds__(256) void prep_k(const float* __restrict__ k,
                                              _Float16* __restrict__ kh) {
  int t = blockIdx.x * 256 + threadIdx.x;       // one thread per 8 elems
  size_t flat = (size_t)t * 8;
  int b = (int)(flat >> 21);                    // S*DIMS = 2^21
  int rem = (int)(flat & ((1u << 21) - 1));
  int s = rem >> 10;
  int c = rem & 1023;
  int h = c >> 6;
  int d = c & 63;
  float4 a0 = *(const float4*)(k + flat);
  float4 a1 = *(const float4*)(k + flat + 4);
  float f[8] = {a0.x, a0.y, a0.z, a0.w, a1.x, a1.y, a1.z, a1.w};
  f16x8 th;
  #pragma unroll
  for (int j = 0; j < 8; ++j) th[j] = (_Float16)f[j];
  size_t o = ((size_t)(b * HEADS + h) * SEQ + s) * DEPTH + d;
  *(f16x8*)(kh + o) = th;
}

// ---------- prepass 2: V fp32 [B,S,DIMS] -> Vt fp16 [bh][D][S] ----------
__global__ __launch_bounds__(256) void prep_v(const float* __restrict__ v,
                                              _Float16* __restrict__ vt) {
  int t = blockIdx.x * 256 + threadIdx.x;
  int d = t & 63;                // lanes cover d contiguously -> coalesced reads
  int sg = (t >> 6) & 255;
  int bh = t >> 14;
  int b = bh >> 4, h = bh & 15;
  int s0 = sg * 8;
  const float* src = v + ((size_t)(b * SEQ + s0)) * DIMS + h * DEPTH + d;
  _Float16* dst = vt + ((size_t)bh * DEPTH + d) * SEQ + s0;
  f16x8 tv;
  #pragma unroll
  for (int i = 0; i < 8; ++i) tv[i] = (_Float16)src[(size_t)i * DIMS];
  *(f16x8*)dst = tv;             // 16B contiguous store
}

// ---------- main: flash attention, KV tile 64, double-buffered ----------
// LDS tiles linear [64][64] fp16 (128B rows), 16B chunks XOR-swizzled:
// data chunk c of row r lives at LDS chunk c^(r&7); K/V source pre-swizzled
// for global_load_lds; P swizzled on both lane write and read.
__global__ __launch_bounds__(256, 4) void attn_fwd(
    const float* __restrict__ q, const _Float16* __restrict__ kh,
    const _Float16* __restrict__ vt, float* __restrict__ out) {
  __shared__ _Float16 Kl[2][64 * 64];
  __shared__ _Float16 Vl[2][64 * 64];
  __shared__ _Float16 Pl[4][16 * 64];

  const int tid = threadIdx.x;
  const int w = tid >> 6;
  const int l = tid & 63;
  const int lg = l >> 4;
  const int lr = l & 15;

  // XCD-chunked bijective swizzle: 1024 blocks = 8 XCDs x 128; consecutive
  // wgs on one XCD share (b,h) -> K/V panel stays in that XCD's L2.
  const int bid = blockIdx.x;
  const int wg = (bid & 7) * 128 + (bid >> 3);
  const int qt = wg & 31;        // q-tile of 64 rows
  const int bh = wg >> 5;        // 0..31
  const int b = bh >> 4;
  const int h = bh & 15;

  const int qb = qt * 64 + w * 16;       // wave's first q row
  const int hoff = h * DEPTH;
  const size_t kvoff = (size_t)bh * SEQ * DEPTH;

  // ---- Q fragments (B-layout: lane holds q-row = lr), scaled by log2e ----
  f16x8 qf[2];
  {
    const float* gq = q + (size_t)(b * SEQ + qb + lr) * DIMS + hoff + 8 * lg;
    #pragma unroll
    for (int c = 0; c < 2; ++c) {
      float4 a0 = *(const float4*)(gq + 32 * c);
      float4 a1 = *(const float4*)(gq + 32 * c + 4);
      float f[8] = {a0.x, a0.y, a0.z, a0.w, a1.x, a1.y, a1.z, a1.w};
      f16x8 t;
      #pragma unroll
      for (int j = 0; j < 8; ++j) t[j] = (_Float16)(f[j] * LOG2E);
      qf[c] = t;
    }
  }

  // ---- per-lane staging source (source column pre-swizzled) ----
  const int srow = l >> 3;                       // row-in-8 for this lane
  const int scol = ((l & 7) ^ srow) * 8;         // inverse-swizzled column
  const _Float16* gk0 = kh + kvoff + (size_t)(16 * w + srow) * DEPTH + scol;
  const _Float16* gv0 = vt + kvoff + (size_t)(16 * w + srow) * SEQ + scol;
  _Float16* Pw = &Pl[w][0];

  f32x4 acc[4] = {};            // C: q = 4*lg+r, d = dt*16+lr
  float mrow = -3e38f;          // log2-domain running max for q-row = lr
  float den = 0.f;

  const int x7 = lr & 7;
  int kch[2];
  #pragma unroll
  for (int c = 0; c < 2; ++c) kch[c] = ((4 * c + lg) ^ x7) * 8;

  // stage tile t into buffer buf (4 x global_load_lds per wave)
  auto stage = [&](int buf, int t) {
    const _Float16* gk = gk0 + (size_t)t * 64 * DEPTH;
    const _Float16* gv = gv0 + (size_t)t * 64;
    GLOAD_LDS(gk, &Kl[buf][(16 * w) * 64]);
    GLOAD_LDS(gk + 8 * DEPTH, &Kl[buf][(16 * w + 8) * 64]);
    GLOAD_LDS(gv, &Vl[buf][(16 * w) * 64]);
    GLOAD_LDS(gv + (size_t)8 * SEQ, &Vl[buf][(16 * w + 8) * 64]);
  };

  auto compute = [&](int buf) {
    // ---- QK^T swapped: C[key][q]; lane holds q=lr, keys nt*16+4lg+r ----
    f32x4 st[4] = {};
    __builtin_amdgcn_s_setprio(1);
    #pragma unroll
    for (int nt = 0; nt < 4; ++nt)
      #pragma unroll
      for (int c = 0; c < 2; ++c) {
        f16x8 kf = *(const f16x8*)&Kl[buf][(nt * 16 + lr) * 64 + kch[c]];
        st[nt] = mfma16(kf, qf[c], st[nt]);
      }
    __builtin_amdgcn_s_setprio(0);

    // ---- online softmax, log2 domain, defer-max (THR=8) ----
    float pmax = st[0][0];
    #pragma unroll
    for (int nt = 0; nt < 4; ++nt)
      #pragma unroll
      for (int r = 0; r < 4; ++r) pmax = fmaxf(pmax, st[nt][r]);
    pmax = fmaxf(pmax, __shfl_xor(pmax, 16));
    pmax = fmaxf(pmax, __shfl_xor(pmax, 32));
    if (!__all(pmax - mrow <= 8.0f)) {
      float mnew = fmaxf(mrow, pmax);
      float sc = EXP2(mrow - mnew);
      mrow = mnew;
      den *= sc;
      #pragma unroll
      for (int r = 0; r < 4; ++r) {
        float scb = __shfl(sc, (l & 48) | (4 * lg + r));
        #pragma unroll
        for (int dt = 0; dt < 4; ++dt) acc[dt][r] *= scb;
      }
    }
    float p[4][4];
    float rs = 0.f;
    #pragma unroll
    for (int nt = 0; nt < 4; ++nt)
      #pragma unroll
      for (int r = 0; r < 4; ++r) {
        p[nt][r] = EXP2(st[nt][r] - mrow);
        rs += p[nt][r];
      }
    rs += __shfl_xor(rs, 16);
    rs += __shfl_xor(rs, 32);
    den += rs;

    // ---- pack P (fp16, swizzled b64 writes): row q=lr, keys nt*16+4lg+r ----
    #pragma unroll
    for (int nt = 0; nt < 4; ++nt) {
      union { fp16v2 h2[2]; f16x4 h4; } pu;
      pu.h2[0] = __builtin_amdgcn_cvt_pkrtz(p[nt][0], p[nt][1]);
      pu.h2[1] = __builtin_amdgcn_cvt_pkrtz(p[nt][2], p[nt][3]);
      const int chunk = (2 * nt + (lg >> 1)) ^ x7;
      *(f16x4*)&Pw[lr * 64 + chunk * 8 + (lg & 1) * 4] = pu.h4;
    }

    // ---- PV: A = P (lane-local q rows), B = V^T; C: q=4lg+r, d=dt*16+lr ----
    __builtin_amdgcn_s_setprio(1);
    #pragma unroll
    for (int ks = 0; ks < 2; ++ks) {
      f16x8 pf = *(const f16x8*)&Pw[lr * 64 + kch[ks]];
      #pragma unroll
      for (int dt = 0; dt < 4; ++dt) {
        f16x8 vf = *(const f16x8*)&Vl[buf][(dt * 16 + lr) * 64 + kch[ks]];
        acc[dt] = mfma16(pf, vf, acc[dt]);
      }
    }
    __builtin_amdgcn_s_setprio(0);
  };

  // ---- 2-phase pipeline: stage t+1 early, ONE barrier per tile ----
  stage(0, 0);
  __syncthreads();                      // drains vmcnt -> tile 0 visible
  for (int kt = 0; kt < SEQ / 64; kt += 2) {
    stage(1, kt + 1);                   // in flight during compute
    compute(0);
    __syncthreads();                    // drain + WAR fence
    if (kt + 2 < SEQ / 64) stage(0, kt + 2);
    compute(1);
    __syncthreads();
  }

  // ---- epilogue: broadcast denominators, normalize, coalesced f32 stores ----
  float rden[4];
  #pragma unroll
  for (int r = 0; r < 4; ++r)
    rden[r] = 1.0f / __shfl(den, (l & 48) | (4 * lg + r));
  #pragma unroll
  for (int dt = 0; dt < 4; ++dt)
    #pragma unroll
    for (int r = 0; r < 4; ++r) {
      const int row = qb + 4 * lg + r;
      out[(size_t)(b * SEQ + row) * DIMS + hoff + dt * 16 + lr] =
          acc[dt][r] * rden[r];
    }
}

extern "C" void kernel_launch(void* const* d_in, const int* in_sizes, int n_in,
                              void* d_out, int out_size, void* d_ws, size_t ws_size,
                              hipStream_t stream) {
  const float* q = (const float*)d_in[0];
  const float* k = (const float*)d_in[1];
  const float* v = (const float*)d_in[2];
  float* out = (float*)d_out;

  // workspace: Khf | Vt, each 2*16*2048*64 fp16 = 8 MiB
  const size_t tsz = (size_t)2 * HEADS * SEQ * DEPTH;  // elements
  _Float16* khf = (_Float16*)d_ws;
  _Float16* vtp = khf + tsz;

  prep_k<<<2048, 256, 0, stream>>>(k, khf);
  prep_v<<<2048, 256, 0, stream>>>(v, vtp);
  attn_fwd<<<1024, 256, 0, stream>>>(q, khf, vtp, out);
}

// Round 7
// 76.685 us; speedup vs baseline: 2.6281x; 1.0137x over previous
//
#include <hip/hip_runtime.h>

#define SEQ 2048
#define HEADS 16
#define DEPTH 64
#define DIMS 1024
#define LOG2E 1.44269504088896340736f

typedef _Float16 f16x8 __attribute__((ext_vector_type(8)));
typedef _Float16 f16x4 __attribute__((ext_vector_type(4)));
typedef __fp16 fp16v2 __attribute__((ext_vector_type(2)));
typedef float f32x4 __attribute__((ext_vector_type(4)));

__device__ __forceinline__ f32x4 mfma16(f16x8 a, f16x8 b, f32x4 c) {
  return __builtin_amdgcn_mfma_f32_16x16x32_f16(a, b, c, 0, 0, 0);
}

#if __has_builtin(__builtin_amdgcn_exp2f)
#define EXP2(x) __builtin_amdgcn_exp2f(x)
#else
#define EXP2(x) exp2f(x)
#endif

// direct global->LDS DMA, 16B/lane; LDS dest = wave-uniform base + lane*16
#define GLOAD_LDS(g, l)                                                        \
  __builtin_amdgcn_global_load_lds(                                            \
      (const __attribute__((address_space(1))) unsigned int*)(g),              \
      (__attribute__((address_space(3))) unsigned int*)(l), 16, 0, 0)

// ---------- prepass 1: K fp32 [B,S,DIMS] -> fp16 [bh][S][D] ----------
__global__ __launch_bounds__(256) void prep_k(const float* __restrict__ k,
                                              _Float16* __restrict__ kh) {
  int t = blockIdx.x * 256 + threadIdx.x;       // one thread per 8 elems
  size_t flat = (size_t)t * 8;
  int b = (int)(flat >> 21);                    // S*DIMS = 2^21
  int rem = (int)(flat & ((1u << 21) - 1));
  int s = rem >> 10;
  int c = rem & 1023;
  int h = c >> 6;
  int d = c & 63;
  float4 a0 = *(const float4*)(k + flat);
  float4 a1 = *(const float4*)(k + flat + 4);
  float f[8] = {a0.x, a0.y, a0.z, a0.w, a1.x, a1.y, a1.z, a1.w};
  f16x8 th;
  #pragma unroll
  for (int j = 0; j < 8; ++j) th[j] = (_Float16)f[j];
  size_t o = ((size_t)(b * HEADS + h) * SEQ + s) * DEPTH + d;
  *(f16x8*)(kh + o) = th;
}

// ---------- prepass 2: V fp32 [B,S,DIMS] -> Vt fp16 [bh][D][S] ----------
__global__ __launch_bounds__(256) void prep_v(const float* __restrict__ v,
                                              _Float16* __restrict__ vt) {
  int t = blockIdx.x * 256 + threadIdx.x;
  int d = t & 63;                // lanes cover d contiguously -> coalesced reads
  int sg = (t >> 6) & 255;
  int bh = t >> 14;
  int b = bh >> 4, h = bh & 15;
  int s0 = sg * 8;
  const float* src = v + ((size_t)(b * SEQ + s0)) * DIMS + h * DEPTH + d;
  _Float16* dst = vt + ((size_t)bh * DEPTH + d) * SEQ + s0;
  f16x8 tv;
  #pragma unroll
  for (int i = 0; i < 8; ++i) tv[i] = (_Float16)src[(size_t)i * DIMS];
  *(f16x8*)dst = tv;             // 16B contiguous store
}

// ---------- main: flash attention, KV tile 64, 32 q-rows/wave, dbuf ----------
// LDS tiles linear [64][64] fp16 (128B rows), 16B chunks XOR-swizzled:
// data chunk c of row r lives at LDS chunk c^(r&7); K/V source pre-swizzled
// for global_load_lds; P swizzled on both lane write and read.
__global__ __launch_bounds__(256, 2) void attn_fwd(
    const float* __restrict__ q, const _Float16* __restrict__ kh,
    const _Float16* __restrict__ vt, float* __restrict__ out) {
  __shared__ _Float16 Kl[2][64 * 64];
  __shared__ _Float16 Vl[2][64 * 64];
  __shared__ _Float16 Pl[4][32 * 64];

  const int tid = threadIdx.x;
  const int w = tid >> 6;
  const int l = tid & 63;
  const int lg = l >> 4;
  const int lr = l & 15;

  // XCD-chunked bijective swizzle: 512 blocks = 8 XCDs x 64; consecutive
  // wgs on one XCD share (b,h) -> K/V panel stays in that XCD's L2.
  const int bid = blockIdx.x;
  const int wg = (bid & 7) * 64 + (bid >> 3);
  const int qt = wg & 15;        // q-tile of 128 rows
  const int bh = wg >> 4;        // 0..31
  const int b = bh >> 4;
  const int h = bh & 15;

  const int qb = qt * 128 + w * 32;      // wave's first q row (32 rows/wave)
  const int hoff = h * DEPTH;
  const size_t kvoff = (size_t)bh * SEQ * DEPTH;

  // ---- Q fragments (B-layout: lane holds q-row = mt*16+lr), *log2e ----
  f16x8 qf[2][2];                        // [mt][c]
  #pragma unroll
  for (int mt = 0; mt < 2; ++mt) {
    const float* gq =
        q + (size_t)(b * SEQ + qb + mt * 16 + lr) * DIMS + hoff + 8 * lg;
    #pragma unroll
    for (int c = 0; c < 2; ++c) {
      float4 a0 = *(const float4*)(gq + 32 * c);
      float4 a1 = *(const float4*)(gq + 32 * c + 4);
      float f[8] = {a0.x, a0.y, a0.z, a0.w, a1.x, a1.y, a1.z, a1.w};
      f16x8 t;
      #pragma unroll
      for (int j = 0; j < 8; ++j) t[j] = (_Float16)(f[j] * LOG2E);
      qf[mt][c] = t;
    }
  }

  // ---- per-lane staging source (source column pre-swizzled) ----
  const int srow = l >> 3;                       // row-in-8 for this lane
  const int scol = ((l & 7) ^ srow) * 8;         // inverse-swizzled column
  const _Float16* gk0 = kh + kvoff + (size_t)(16 * w + srow) * DEPTH + scol;
  const _Float16* gv0 = vt + kvoff + (size_t)(16 * w + srow) * SEQ + scol;
  _Float16* Pw = &Pl[w][0];

  f32x4 acc[2][4] = {};         // [mt][dt]; C: q = mt*16+4lg+r, d = dt*16+lr
  float mrow[2] = {-3e38f, -3e38f};   // running max (log2 domain), q-row lr
  float den[2] = {0.f, 0.f};

  const int x7 = lr & 7;
  int kch[2];
  #pragma unroll
  for (int c = 0; c < 2; ++c) kch[c] = ((4 * c + lg) ^ x7) * 8;

  // stage tile t into buffer buf (4 x global_load_lds per wave)
  auto stage = [&](int buf, int t) {
    const _Float16* gk = gk0 + (size_t)t * 64 * DEPTH;
    const _Float16* gv = gv0 + (size_t)t * 64;
    GLOAD_LDS(gk, &Kl[buf][(16 * w) * 64]);
    GLOAD_LDS(gk + 8 * DEPTH, &Kl[buf][(16 * w + 8) * 64]);
    GLOAD_LDS(gv, &Vl[buf][(16 * w) * 64]);
    GLOAD_LDS(gv + (size_t)8 * SEQ, &Vl[buf][(16 * w + 8) * 64]);
  };

  auto compute = [&](int buf) {
    // ---- QK^T swapped: C[key][q]; lane holds q-col lr, keys nt*16+4lg+r ----
    // K fragment reads shared by both q-sets: 8 reads -> 16 MFMAs.
    f32x4 st[2][4] = {};
    __builtin_amdgcn_s_setprio(1);
    #pragma unroll
    for (int nt = 0; nt < 4; ++nt)
      #pragma unroll
      for (int c = 0; c < 2; ++c) {
        f16x8 kf = *(const f16x8*)&Kl[buf][(nt * 16 + lr) * 64 + kch[c]];
        st[0][nt] = mfma16(kf, qf[0][c], st[0][nt]);
        st[1][nt] = mfma16(kf, qf[1][c], st[1][nt]);
      }
    __builtin_amdgcn_s_setprio(0);

    // ---- per-set online softmax (log2 domain, defer-max THR=8) + P pack ----
    #pragma unroll
    for (int mt = 0; mt < 2; ++mt) {
      float pmax = st[mt][0][0];
      #pragma unroll
      for (int nt = 0; nt < 4; ++nt)
        #pragma unroll
        for (int r = 0; r < 4; ++r) pmax = fmaxf(pmax, st[mt][nt][r]);
      pmax = fmaxf(pmax, __shfl_xor(pmax, 16));
      pmax = fmaxf(pmax, __shfl_xor(pmax, 32));
      if (!__all(pmax - mrow[mt] <= 8.0f)) {
        float mnew = fmaxf(mrow[mt], pmax);
        float sc = EXP2(mrow[mt] - mnew);
        mrow[mt] = mnew;
        den[mt] *= sc;
        #pragma unroll
        for (int r = 0; r < 4; ++r) {
          float scb = __shfl(sc, (l & 48) | (4 * lg + r));
          #pragma unroll
          for (int dt = 0; dt < 4; ++dt) acc[mt][dt][r] *= scb;
        }
      }
      float rs = 0.f;
      #pragma unroll
      for (int nt = 0; nt < 4; ++nt) {
        float p0 = EXP2(st[mt][nt][0] - mrow[mt]);
        float p1 = EXP2(st[mt][nt][1] - mrow[mt]);
        float p2 = EXP2(st[mt][nt][2] - mrow[mt]);
        float p3 = EXP2(st[mt][nt][3] - mrow[mt]);
        rs += (p0 + p1) + (p2 + p3);
        union { fp16v2 h2[2]; f16x4 h4; } pu;
        pu.h2[0] = __builtin_amdgcn_cvt_pkrtz(p0, p1);
        pu.h2[1] = __builtin_amdgcn_cvt_pkrtz(p2, p3);
        const int chunk = (2 * nt + (lg >> 1)) ^ x7;
        *(f16x4*)&Pw[(mt * 16 + lr) * 64 + chunk * 8 + (lg & 1) * 4] = pu.h4;
      }
      rs += __shfl_xor(rs, 16);
      rs += __shfl_xor(rs, 32);
      den[mt] += rs;
    }

    // ---- PV: A = P (lane-local q rows), B = V^T; V reads shared by sets ----
    __builtin_amdgcn_s_setprio(1);
    #pragma unroll
    for (int ks = 0; ks < 2; ++ks) {
      f16x8 pf0 = *(const f16x8*)&Pw[(0 * 16 + lr) * 64 + kch[ks]];
      f16x8 pf1 = *(const f16x8*)&Pw[(1 * 16 + lr) * 64 + kch[ks]];
      #pragma unroll
      for (int dt = 0; dt < 4; ++dt) {
        f16x8 vf = *(const f16x8*)&Vl[buf][(dt * 16 + lr) * 64 + kch[ks]];
        acc[0][dt] = mfma16(pf0, vf, acc[0][dt]);
        acc[1][dt] = mfma16(pf1, vf, acc[1][dt]);
      }
    }
    __builtin_amdgcn_s_setprio(0);
  };

  // ---- 2-phase pipeline: stage t+1 early, ONE barrier per tile ----
  stage(0, 0);
  __syncthreads();                      // drains vmcnt -> tile 0 visible
  for (int kt = 0; kt < SEQ / 64; kt += 2) {
    stage(1, kt + 1);                   // in flight during compute
    compute(0);
    __syncthreads();                    // drain + WAR fence
    if (kt + 2 < SEQ / 64) stage(0, kt + 2);
    compute(1);
    __syncthreads();
  }

  // ---- epilogue: broadcast denominators, normalize, coalesced f32 stores ----
  #pragma unroll
  for (int mt = 0; mt < 2; ++mt) {
    float rden[4];
    #pragma unroll
    for (int r = 0; r < 4; ++r)
      rden[r] = 1.0f / __shfl(den[mt], (l & 48) | (4 * lg + r));
    #pragma unroll
    for (int dt = 0; dt < 4; ++dt)
      #pragma unroll
      for (int r = 0; r < 4; ++r) {
        const int row = qb + mt * 16 + 4 * lg + r;
        out[(size_t)(b * SEQ + row) * DIMS + hoff + dt * 16 + lr] =
            acc[mt][dt][r] * rden[r];
      }
  }
}

extern "C" void kernel_launch(void* const* d_in, const int* in_sizes, int n_in,
                              void* d_out, int out_size, void* d_ws, size_t ws_size,
                              hipStream_t stream) {
  const float* q = (const float*)d_in[0];
  const float* k = (const float*)d_in[1];
  const float* v = (const float*)d_in[2];
  float* out = (float*)d_out;

  // workspace: Khf | Vt, each 2*16*2048*64 fp16 = 8 MiB
  const size_t tsz = (size_t)2 * HEADS * SEQ * DEPTH;  // elements
  _Float16* khf = (_Float16*)d_ws;
  _Float16* vtp = khf + tsz;

  prep_k<<<2048, 256, 0, stream>>>(k, khf);
  prep_v<<<2048, 256, 0, stream>>>(v, vtp);
  attn_fwd<<<512, 256, 0, stream>>>(q, khf, vtp, out);
}